// Round 5
// baseline (129.223 us; speedup 1.0000x reference)
//
#include <hip/hip_runtime.h>
#include <hip/hip_bf16.h>
#include <hip/hip_cooperative_groups.h>
#include <math.h>

// EquivEncoder: B=16, N_CTX=1024, 64x64 grid, fp32.
// out[b,c,iy,ix]: c0 = dens = sum_n w, c1 = (sum_n w*y0)/dens, c2 = (sum_n w*y1)/dens
// w = exp2(s*dx^2)*exp2(s*dy^2), s = -0.5*log2(e)*exp(-2*logl)
//
// R5 design (R3 kernels were fast; 2-dispatch overhead was the residual;
//            R4 proved a thin-tile single kernel regresses):
//  - ONE cooperative kernel: phase1 = R3's ee_partial (16 b x 16 n-chunks,
//    4x4 register tile/thread, 2.5 B LDS per entry), grid.sync(),
//    phase2 = reduce 16 partials + divide (65536 threads = one per (b,g)).
//  - 256 blocks <= 256 CUs -> co-residency guaranteed for cooperative launch.
//  - grid.sync() supplies the device-scope fence needed for the cross-XCD
//    ws round-trip (G16).

#define NB     16
#define NCTX   1024
#define NG     4096
#define NSPLIT 16
#define NC     64      // NCTX / NSPLIT

namespace cg = cooperative_groups;

__global__ __launch_bounds__(256, 1)
void ee_coop(const float* __restrict__ X,
             const float* __restrict__ Y,
             const float* __restrict__ log_l_scale,
             float* ws,
             float* __restrict__ out) {
    // ---------------- phase 1: partial sums (R3 structure) ----------------
    const int b  = blockIdx.x >> 4;
    const int nc = blockIdx.x & 15;
    const int n0 = nc * NC;

    const float step  = 20.0f / 63.0f;
    const float scale = -0.72134752044448170f * expf(-2.0f * log_l_scale[0]);

    __shared__ float  wx[NC][64];    // 16 KB  exp2(s*dx^2) for (n, ix)
    __shared__ float  wy[NC][64];    // 16 KB  exp2(s*dy^2) for (n, iy)
    __shared__ float2 sy[NC];        // 512 B  (y0, y1)

    const float2* Xb = (const float2*)(X + (size_t)b * NCTX * 2);
    const float2* Yb = (const float2*)(Y + (size_t)b * NCTX * 2);

    for (int idx = threadIdx.x; idx < NC * 64; idx += 256) {
        const int j = idx >> 6, i = idx & 63;
        const float2 xv = Xb[n0 + j];
        const float dx = (-10.0f + step * (float)i) - xv.x;
        const float dy = ( 10.0f - step * (float)i) - xv.y;
        wx[j][i] = exp2f(dx * dx * scale);
        wy[j][i] = exp2f(dy * dy * scale);
    }
    if (threadIdx.x < NC) sy[threadIdx.x] = Yb[n0 + threadIdx.x];
    __syncthreads();

    const int tx = threadIdx.x & 15;
    const int ty = threadIdx.x >> 4;
    const int ix0 = tx * 4;
    const int iy0 = ty * 4;

    float4 ad[4] = {{0,0,0,0},{0,0,0,0},{0,0,0,0},{0,0,0,0}};  // dens
    float4 a1[4] = {{0,0,0,0},{0,0,0,0},{0,0,0,0},{0,0,0,0}};  // sum w*y0
    float4 a2[4] = {{0,0,0,0},{0,0,0,0},{0,0,0,0},{0,0,0,0}};  // sum w*y1

#pragma unroll 4
    for (int n = 0; n < NC; ++n) {
        const float4 wxv = *(const float4*)&wx[n][ix0];  // contiguous row b128
        const float4 wyv = *(const float4*)&wy[n][iy0];  // 4-addr broadcast b128
        const float2 yv  = sy[n];                        // full broadcast
        const float wys[4] = {wyv.x, wyv.y, wyv.z, wyv.w};
#pragma unroll
        for (int s = 0; s < 4; ++s) {
            const float w  = wys[s];
            const float q1 = w * yv.x;
            const float q2 = w * yv.y;
            ad[s].x = fmaf(wxv.x, w, ad[s].x);  ad[s].y = fmaf(wxv.y, w, ad[s].y);
            ad[s].z = fmaf(wxv.z, w, ad[s].z);  ad[s].w = fmaf(wxv.w, w, ad[s].w);
            a1[s].x = fmaf(wxv.x, q1, a1[s].x); a1[s].y = fmaf(wxv.y, q1, a1[s].y);
            a1[s].z = fmaf(wxv.z, q1, a1[s].z); a1[s].w = fmaf(wxv.w, q1, a1[s].w);
            a2[s].x = fmaf(wxv.x, q2, a2[s].x); a2[s].y = fmaf(wxv.y, q2, a2[s].y);
            a2[s].z = fmaf(wxv.z, q2, a2[s].z); a2[s].w = fmaf(wxv.w, q2, a2[s].w);
        }
    }

    {   // partials: ws[b][nc][c][g], float4 stores
        float* base = ws + ((size_t)(b * NSPLIT + nc)) * 3 * NG;
#pragma unroll
        for (int s = 0; s < 4; ++s) {
            const int g = (iy0 + s) * 64 + ix0;
            *(float4*)&base[g]        = ad[s];
            *(float4*)&base[NG + g]   = a1[s];
            *(float4*)&base[2*NG + g] = a2[s];
        }
    }

    // ---------------- grid-wide barrier (device-scope fence) ----------------
    cg::this_grid().sync();

    // ---------------- phase 2: reduce + divide ----------------
    const int t  = blockIdx.x * 256 + threadIdx.x;   // 65536 = 16*4096
    const int rb = t >> 12, g = t & 4095;
    const float* rbase = ws + (size_t)rb * NSPLIT * 3 * NG;
    float r0 = 0, r1 = 0, r2 = 0;
#pragma unroll
    for (int k = 0; k < NSPLIT; ++k) {
        const float* p = rbase + k * 3 * NG;
        r0 += p[g];
        r1 += p[NG + g];
        r2 += p[2 * NG + g];
    }
    const float inv = 1.0f / r0;   // r0 > 0 (sum of exps)
    float* ob = out + (size_t)rb * 3 * NG;
    ob[g]          = r0;
    ob[NG + g]     = r1 * inv;
    ob[2 * NG + g] = r2 * inv;
}

extern "C" void kernel_launch(void* const* d_in, const int* in_sizes, int n_in,
                              void* d_out, int out_size, void* d_ws, size_t ws_size,
                              hipStream_t stream) {
    const float* X    = (const float*)d_in[0];   // (16,1024,2) fp32
    const float* Y    = (const float*)d_in[1];   // (16,1024,2) fp32
    const float* logl = (const float*)d_in[2];   // scalar fp32
    float* out = (float*)d_out;                  // (16,3,64,64) fp32
    float* ws  = (float*)d_ws;                   // 16*16*3*4096*4 = 12.6 MB

    void* args[] = {(void*)&X, (void*)&Y, (void*)&logl, (void*)&ws, (void*)&out};
    hipLaunchCooperativeKernel((const void*)ee_coop, dim3(NB * NSPLIT), dim3(256),
                               args, 0, stream);
}

// Round 6
// 96.451 us; speedup vs baseline: 1.3398x; 1.3398x over previous
//
#include <hip/hip_runtime.h>
#include <hip/hip_bf16.h>
#include <math.h>

// EquivEncoder: B=16, N_CTX=1024, 64x64 grid, fp32.
// out[b,c,iy,ix]: c0 = dens = sum_n w, c1 = (sum_n w*y0)/dens, c2 = (sum_n w*y1)/dens
// w = exp2(s*dx^2)*exp2(s*dy^2), s = -0.5*log2(e)*exp(-2*logl)
//
// R6 design (R5 measured grid.sync at ~47 us + ~35 us launch cost; phase
// compute is only ~4 us -> replace the barrier, keep everything else):
//  - ONE regular dispatch. Phase1 = R3 partial (16 b x 16 nc blocks, 4x4
//    register tile, 2.5 B LDS/entry, ~3.5 us). Partials -> ws.
//  - Combine via per-block release flags (agent scope) + spin-acquire:
//    block (b,nc) waits for batch b's 16 flags, then reduces its own
//    256-cell slice (48 KB coalesced). Flags live past the partials in ws;
//    poison 0xAA.. != MAGIC so no init dispatch needed (harness re-poisons
//    ws before every launch).
//  - All 256 blocks co-resident (33 KB LDS, ~64 VGPR) -> no deadlock.

#define NB     16
#define NCTX   1024
#define NG     4096
#define NSPLIT 16
#define NC     64      // NCTX / NSPLIT
#define MAGIC  0x13579BDFu

__global__ __launch_bounds__(256, 1)
void ee_onepass(const float* __restrict__ X,
                const float* __restrict__ Y,
                const float* __restrict__ log_l_scale,
                float* ws,
                float* __restrict__ out) {
    // ---------------- phase 1: partial sums (R3 structure) ----------------
    const int b  = blockIdx.x >> 4;
    const int nc = blockIdx.x & 15;
    const int n0 = nc * NC;

    const float step  = 20.0f / 63.0f;
    const float scale = -0.72134752044448170f * expf(-2.0f * log_l_scale[0]);

    __shared__ float  wx[NC][64];    // 16 KB  exp2(s*dx^2) for (n, ix)
    __shared__ float  wy[NC][64];    // 16 KB  exp2(s*dy^2) for (n, iy)
    __shared__ float2 sy[NC];        // 512 B  (y0, y1)

    const float2* Xb = (const float2*)(X + (size_t)b * NCTX * 2);
    const float2* Yb = (const float2*)(Y + (size_t)b * NCTX * 2);

    for (int idx = threadIdx.x; idx < NC * 64; idx += 256) {
        const int j = idx >> 6, i = idx & 63;
        const float2 xv = Xb[n0 + j];
        const float dx = (-10.0f + step * (float)i) - xv.x;
        const float dy = ( 10.0f - step * (float)i) - xv.y;
        wx[j][i] = exp2f(dx * dx * scale);
        wy[j][i] = exp2f(dy * dy * scale);
    }
    if (threadIdx.x < NC) sy[threadIdx.x] = Yb[n0 + threadIdx.x];
    __syncthreads();

    const int tx = threadIdx.x & 15;
    const int ty = threadIdx.x >> 4;
    const int ix0 = tx * 4;
    const int iy0 = ty * 4;

    float4 ad[4] = {{0,0,0,0},{0,0,0,0},{0,0,0,0},{0,0,0,0}};  // dens
    float4 a1[4] = {{0,0,0,0},{0,0,0,0},{0,0,0,0},{0,0,0,0}};  // sum w*y0
    float4 a2[4] = {{0,0,0,0},{0,0,0,0},{0,0,0,0},{0,0,0,0}};  // sum w*y1

#pragma unroll 4
    for (int n = 0; n < NC; ++n) {
        const float4 wxv = *(const float4*)&wx[n][ix0];  // contiguous row b128
        const float4 wyv = *(const float4*)&wy[n][iy0];  // 4-addr broadcast b128
        const float2 yv  = sy[n];                        // full broadcast
        const float wys[4] = {wyv.x, wyv.y, wyv.z, wyv.w};
#pragma unroll
        for (int s = 0; s < 4; ++s) {
            const float w  = wys[s];
            const float q1 = w * yv.x;
            const float q2 = w * yv.y;
            ad[s].x = fmaf(wxv.x, w, ad[s].x);  ad[s].y = fmaf(wxv.y, w, ad[s].y);
            ad[s].z = fmaf(wxv.z, w, ad[s].z);  ad[s].w = fmaf(wxv.w, w, ad[s].w);
            a1[s].x = fmaf(wxv.x, q1, a1[s].x); a1[s].y = fmaf(wxv.y, q1, a1[s].y);
            a1[s].z = fmaf(wxv.z, q1, a1[s].z); a1[s].w = fmaf(wxv.w, q1, a1[s].w);
            a2[s].x = fmaf(wxv.x, q2, a2[s].x); a2[s].y = fmaf(wxv.y, q2, a2[s].y);
            a2[s].z = fmaf(wxv.z, q2, a2[s].z); a2[s].w = fmaf(wxv.w, q2, a2[s].w);
        }
    }

    {   // partials: ws[b][nc][c][g], float4 stores
        float* base = ws + ((size_t)(b * NSPLIT + nc)) * 3 * NG;
#pragma unroll
        for (int s = 0; s < 4; ++s) {
            const int g = (iy0 + s) * 64 + ix0;
            *(float4*)&base[g]        = ad[s];
            *(float4*)&base[NG + g]   = a1[s];
            *(float4*)&base[2*NG + g] = a2[s];
        }
    }

    // -------- publish: block-wide drain, then agent-scope release flag --------
    unsigned* flags = (unsigned*)(ws + (size_t)NB * NSPLIT * 3 * NG);
    __syncthreads();                 // all block stores issued & drained (vmcnt0)
    if (threadIdx.x == 0) {
        __threadfence();             // agent-scope fence: L2 writeback
        __hip_atomic_store(&flags[blockIdx.x], MAGIC,
                           __ATOMIC_RELEASE, __HIP_MEMORY_SCOPE_AGENT);
    }

    // -------- wait for this batch's 16 producers (acquire) --------
    if (threadIdx.x < NSPLIT) {
        const int fi = b * NSPLIT + threadIdx.x;
        while (__hip_atomic_load(&flags[fi], __ATOMIC_ACQUIRE,
                                 __HIP_MEMORY_SCOPE_AGENT) != MAGIC) {
            __builtin_amdgcn_s_sleep(4);
        }
    }
    __syncthreads();

    // ---------------- phase 2: reduce own 256-cell slice + divide ----------------
    const int g = nc * 256 + threadIdx.x;
    const float* rbase = ws + (size_t)b * NSPLIT * 3 * NG;
    float r0 = 0, r1 = 0, r2 = 0;
#pragma unroll
    for (int k = 0; k < NSPLIT; ++k) {
        const float* p = rbase + k * 3 * NG;
        r0 += p[g];
        r1 += p[NG + g];
        r2 += p[2 * NG + g];
    }
    const float inv = 1.0f / r0;   // r0 > 0 (sum of exps)
    float* ob = out + (size_t)b * 3 * NG;
    ob[g]          = r0;
    ob[NG + g]     = r1 * inv;
    ob[2 * NG + g] = r2 * inv;
}

extern "C" void kernel_launch(void* const* d_in, const int* in_sizes, int n_in,
                              void* d_out, int out_size, void* d_ws, size_t ws_size,
                              hipStream_t stream) {
    const float* X    = (const float*)d_in[0];   // (16,1024,2) fp32
    const float* Y    = (const float*)d_in[1];   // (16,1024,2) fp32
    const float* logl = (const float*)d_in[2];   // scalar fp32
    float* out = (float*)d_out;                  // (16,3,64,64) fp32
    float* ws  = (float*)d_ws;                   // 12.6 MB partials + 1 KB flags

    ee_onepass<<<dim3(NB * NSPLIT), dim3(256), 0, stream>>>(X, Y, logl, ws, out);
}

// Round 7
// 85.326 us; speedup vs baseline: 1.5145x; 1.1304x over previous
//
#include <hip/hip_runtime.h>
#include <hip/hip_bf16.h>
#include <math.h>

// EquivEncoder: B=16, N_CTX=1024, 64x64 grid, fp32.
// out[b,c,iy,ix]: c0 = dens = sum_n w, c1 = (sum_n w*y0)/dens, c2 = (sum_n w*y1)/dens
// w = exp2(d2 * s), s = -0.5*log2(e)*exp(-2*logl)
//
// R7 design (R5/R6 measured: ANY cross-XCD sync in-kernel costs 35-47 us;
// the only cheap combine is intra-block):
//  - ONE dispatch, 256 blocks (16 b x 16 tiles of 256 cells) x 1024 threads.
//    thread = (cell c, n-quarter q); each thread: 256 n of the direct formula
//    (8 VALU + 1 exp2 per entry -> device VALU floor 6.8 us).
//  - X[n],Y[n] are wave-uniform (q is constant per wave): readfirstlane the
//    n-base so the compiler proves uniformity and emits s_load (no LDS, no
//    per-lane VMEM in the hot loop -- dodges R4's LDS-issue wall and R1's
//    latency wall). 16 waves/CU hide the s_load latency.
//  - combine the 4 n-quarters through 9 KB of LDS, q==0 divides + stores.
//  - no ws, no flags, no fences, no second dispatch.

#define NB    16
#define NCTX  1024
#define NG    4096
#define NQ    4              // n-quarters per block
#define NPQ   (NCTX / NQ)    // 256 n per quarter
#define CELLS 256            // cells per block

__global__ __launch_bounds__(1024, 1)
void ee_single(const float* __restrict__ X,
               const float* __restrict__ Y,
               const float* __restrict__ log_l_scale,
               float* __restrict__ out) {
    const int b    = blockIdx.x >> 4;
    const int tile = blockIdx.x & 15;
    const int tid  = threadIdx.x;
    const int c    = tid & 255;        // cell within tile
    const int q    = tid >> 8;         // n-quarter 0..3 (constant per wave)
    const int ix   = c & 63;
    const int iy   = tile * 4 + (c >> 6);

    const float step  = 20.0f / 63.0f;
    const float scale = -0.72134752044448170f * expf(-2.0f * log_l_scale[0]);
    const float gx = -10.0f + step * (float)ix;
    const float gy =  10.0f - step * (float)iy;

    // q is wave-uniform; readfirstlane makes it *provably* uniform so the
    // address Xb[n0+i] scalarizes to s_load_dwordx2.
    const int n0 = __builtin_amdgcn_readfirstlane(q * NPQ);

    const float2* Xb = (const float2*)(X + (size_t)b * NCTX * 2);
    const float2* Yb = (const float2*)(Y + (size_t)b * NCTX * 2);

    float d = 0.0f, a1 = 0.0f, a2 = 0.0f;
#pragma unroll 8
    for (int i = 0; i < NPQ; ++i) {
        const float2 xv = Xb[n0 + i];   // uniform -> s_load_dwordx2
        const float2 yv = Yb[n0 + i];   // uniform -> s_load_dwordx2
        const float dx = gx - xv.x;
        const float dy = gy - xv.y;
        float d2 = dx * dx;
        d2 = fmaf(dy, dy, d2);
        const float w = exp2f(d2 * scale);   // v_exp_f32 (trans pipe, overlaps)
        d  += w;
        a1 = fmaf(w, yv.x, a1);
        a2 = fmaf(w, yv.y, a2);
    }

    // ---- intra-block combine over the 4 n-quarters (9 KB LDS) ----
    __shared__ float red[(NQ - 1) * CELLS * 3];
    if (q > 0) {
        float* r = &red[((q - 1) * CELLS + c) * 3];
        r[0] = d; r[1] = a1; r[2] = a2;
    }
    __syncthreads();
    if (q == 0) {
#pragma unroll
        for (int k = 0; k < NQ - 1; ++k) {
            const float* r = &red[(k * CELLS + c) * 3];
            d  += r[0];
            a1 += r[1];
            a2 += r[2];
        }
        const int g = tile * 256 + c;       // = iy*64 + ix
        const float inv = 1.0f / d;         // d > 0 (sum of exps)
        float* ob = out + (size_t)b * 3 * NG;
        ob[g]          = d;
        ob[NG + g]     = a1 * inv;
        ob[2 * NG + g] = a2 * inv;
    }
}

extern "C" void kernel_launch(void* const* d_in, const int* in_sizes, int n_in,
                              void* d_out, int out_size, void* d_ws, size_t ws_size,
                              hipStream_t stream) {
    const float* X    = (const float*)d_in[0];   // (16,1024,2) fp32
    const float* Y    = (const float*)d_in[1];   // (16,1024,2) fp32
    const float* logl = (const float*)d_in[2];   // scalar fp32
    float* out = (float*)d_out;                  // (16,3,64,64) fp32

    ee_single<<<dim3(NB * 16), dim3(1024), 0, stream>>>(X, Y, logl, out);
}

// Round 8
// 79.092 us; speedup vs baseline: 1.6338x; 1.0788x over previous
//
#include <hip/hip_runtime.h>
#include <hip/hip_bf16.h>
#include <math.h>

// EquivEncoder: B=16, N_CTX=1024, 64x64 grid, fp32.
// out[b,c,iy,ix]: c0 = dens = sum_n w, c1 = (sum_n w*y0)/dens, c2 = (sum_n w*y1)/dens
// w = exp2(d2 * s), s = -0.5*log2(e)*exp(-2*logl)
//
// R8 design. Calibration from R1-R7: cost/entry of the staged operand stream
// ~= wave_mem_ops_cyc / (64 * cells_per_thread). R4/R7 died at cpt=1. Here:
//  - ONE dispatch, 256 blocks = 16 b x 16 tiles (4 iy x 64 ix), 1024 threads
//    = 16 waves = 16 n-chunks of 64. Lane = ix, thread covers all 4 iy (cpt=4)
//    -> ONE broadcast ds_read_b128 per (wave, n) feeds 256 entries.
//  - direct formula, x-side shared across the 4 iy: 26 VALU + 4 exp2 per n
//    = 6.5 VALU/entry -> 5.5 us VALU floor; LDS <= 5 us; trans 3.4 us overlap.
//  - combine: 16 waves -> 48 KB LDS, one barrier, first 256 threads reduce
//    16 partials/cell, divide, store. No ws, no cross-block sync.

#define NB    16
#define NCTX  1024
#define NG    4096
#define NW    16     // waves per block = n-chunks
#define NPW   64     // n per wave

__global__ __launch_bounds__(1024, 1)
void ee_single2(const float* __restrict__ X,
                const float* __restrict__ Y,
                const float* __restrict__ log_l_scale,
                float* __restrict__ out) {
    const int b    = blockIdx.x >> 4;
    const int tile = blockIdx.x & 15;
    const int tid  = threadIdx.x;
    const int q    = tid >> 6;          // wave = n-chunk 0..15
    const int l    = tid & 63;          // lane = ix

    const float step  = 20.0f / 63.0f;
    const float scale = -0.72134752044448170f * expf(-2.0f * log_l_scale[0]);
    const float gx = -10.0f + step * (float)l;
    float gy[4];
#pragma unroll
    for (int k = 0; k < 4; ++k)
        gy[k] = 10.0f - step * (float)(tile * 4 + k);

    // ---- stage all context points once: {x0, x1, y0, y1} ----
    __shared__ float4 sxy[NCTX];               // 16 KB
    __shared__ float  red[NW][3][256];         // 48 KB partials
    {
        const float2* Xb = (const float2*)(X + (size_t)b * NCTX * 2);
        const float2* Yb = (const float2*)(Y + (size_t)b * NCTX * 2);
        const float2 xv = Xb[tid];
        const float2 yv = Yb[tid];
        sxy[tid] = make_float4(xv.x, xv.y, yv.x, yv.y);
    }
    __syncthreads();

    // ---- each wave: its 64-n chunk over the full 4x64 tile ----
    float d[4] = {0, 0, 0, 0}, a1[4] = {0, 0, 0, 0}, a2[4] = {0, 0, 0, 0};
    const int n0 = q * NPW;
#pragma unroll 4
    for (int i = 0; i < NPW; ++i) {
        const float4 v = sxy[n0 + i];          // full-wave broadcast b128
        const float dx = gx - v.x;
        const float tb = (dx * dx) * scale;    // shared across 4 iy
#pragma unroll
        for (int k = 0; k < 4; ++k) {
            const float dy = gy[k] - v.y;
            const float t  = fmaf(dy * scale, dy, tb);
            const float w  = exp2f(t);         // v_exp_f32
            d[k]  += w;
            a1[k]  = fmaf(w, v.z, a1[k]);
            a2[k]  = fmaf(w, v.w, a2[k]);
        }
    }

    // ---- combine 16 waves' partials via LDS ----
#pragma unroll
    for (int k = 0; k < 4; ++k) {
        const int c = k * 64 + l;              // cell within tile
        red[q][0][c] = d[k];
        red[q][1][c] = a1[k];
        red[q][2][c] = a2[k];
    }
    __syncthreads();

    if (tid < 256) {                           // waves 0..3: one cell each
        const int c = tid;
        float r0 = 0, r1 = 0, r2 = 0;
#pragma unroll
        for (int k = 0; k < NW; ++k) {         // coalesced b32 rows
            r0 += red[k][0][c];
            r1 += red[k][1][c];
            r2 += red[k][2][c];
        }
        const int g = tile * 256 + c;          // = iy*64 + ix
        const float inv = 1.0f / r0;           // r0 > 0 (sum of exps)
        float* ob = out + (size_t)b * 3 * NG;
        ob[g]          = r0;
        ob[NG + g]     = r1 * inv;
        ob[2 * NG + g] = r2 * inv;
    }
}

extern "C" void kernel_launch(void* const* d_in, const int* in_sizes, int n_in,
                              void* d_out, int out_size, void* d_ws, size_t ws_size,
                              hipStream_t stream) {
    const float* X    = (const float*)d_in[0];   // (16,1024,2) fp32
    const float* Y    = (const float*)d_in[1];   // (16,1024,2) fp32
    const float* logl = (const float*)d_in[2];   // scalar fp32
    float* out = (float*)d_out;                  // (16,3,64,64) fp32

    ee_single2<<<dim3(256), dim3(1024), 0, stream>>>(X, Y, logl, out);
}